// Round 12
// baseline (911.331 us; speedup 1.0000x reference)
//
#include <hip/hip_runtime.h>
#include <hip/hip_bf16.h>
#include <stdint.h>

typedef __attribute__((ext_vector_type(8))) short short8;
typedef __attribute__((ext_vector_type(4))) float floatx4;
typedef __attribute__((ext_vector_type(2))) uint uint2v;

#define INV_SQRT2F 0.70710678118654752440f
#define ROWS 128
#define NT 256

// fragment-ordered bf16 weights (8.5 MB), filled by k_cvt each call
__device__ ushort g_wbuf[4259840];

__device__ __forceinline__ ushort f2bf(float f) {
    union { float f; uint32_t u; } c; c.f = f;
    uint32_t x = c.u;
    return (ushort)((x + 0x7fffu + ((x >> 16) & 1u)) >> 16);  // RTNE
}
__device__ __forceinline__ uint pk2bf(float a, float b) {   // v_cvt_pk_bf16_f32
    union { __hip_bfloat162 h; uint u; } c;
    c.h = __float22bfloat162_rn(make_float2(a, b));
    return c.u;
}
__device__ __forceinline__ float softplus100(float x) {
    float z = 100.f * x;
    return fmaxf(x, 0.f) + __logf(1.f + __expf(-fabsf(z))) * 0.01f;
}
// barrier that waits only on LDS ops: weight loads (vmcnt) stay in flight
// across it (T4: never drain vmcnt to 0 in the layer loop).
__device__ __forceinline__ void bar_lgkm() {
    asm volatile("s_waitcnt lgkmcnt(0)\n\ts_barrier" ::: "memory");
}
// fragment-major index (in shorts) of (row, ch) for a layout with K32 kc-groups:
// elem j of lane (q*16+li) at (m,kc) is row = m*16+li, ch = kc*32 + q*8 + j.
__device__ __forceinline__ int fidx(int K32, int row, int ch) {
    return (((row >> 4) * K32 + (ch >> 5)) * 64 + ((ch >> 3) & 3) * 16 + (row & 15)) * 8 + (ch & 7);
}

// ---------------- weight cvt + fragment reorder ----------------
struct Seg { const float* s; int off, nout, kw, k32, ttot, nclust; };
struct CvtAll { Seg seg[16]; };

__global__ void k_cvt(CvtAll c) {
    Seg sg = c.seg[blockIdx.y];
    ushort* d = g_wbuf + sg.off;
    const int pcs8 = sg.ttot * sg.k32 * 64;
    const int tot8 = pcs8 * sg.nclust;
    const bool vec = ((sg.kw & 7) == 0);   // full-width aligned path (kw=512/128)
    for (int i8 = blockIdx.x * blockDim.x + threadIdx.x; i8 < tot8;
         i8 += gridDim.x * blockDim.x) {
        int cl = i8 / pcs8;
        int r = i8 - cl * pcs8;
        int t = r / (sg.k32 * 64);
        int r2 = r - t * (sg.k32 * 64);
        int kc = r2 >> 6;
        int lane = r2 & 63;
        int n = t * 16 + (lane & 15);
        int kb = kc * 32 + (lane >> 4) * 8;
        const float* src = sg.s + (size_t)cl * sg.nout * sg.kw;
        short8 v = {0, 0, 0, 0, 0, 0, 0, 0};
        if (n < sg.nout) {
            if (vec && kb + 8 <= sg.kw) {
                // 2x dwordx4 instead of 8 scalar loads (16B-aligned: kw%8==0, kb%8==0)
                const float4* s4 = (const float4*)(src + (size_t)n * sg.kw + kb);
                float4 a = s4[0], b = s4[1];
                v[0] = (short)f2bf(a.x); v[1] = (short)f2bf(a.y);
                v[2] = (short)f2bf(a.z); v[3] = (short)f2bf(a.w);
                v[4] = (short)f2bf(b.x); v[5] = (short)f2bf(b.y);
                v[6] = (short)f2bf(b.z); v[7] = (short)f2bf(b.w);
            } else {
#pragma unroll
                for (int j = 0; j < 8; ++j) {
                    int k = kb + j;
                    if (k < sg.kw) v[j] = (short)f2bf(src[(size_t)n * sg.kw + k]);
                }
            }
        }
        *(short8*)(d + (size_t)i8 * 8) = v;
    }
}

// ---------------- embedding: ROWS rows, cols 0..63 (zeros beyond 38) ----------------
template<int K32OUT>
__device__ void embedR(short* act, const float* pts, int row0, short* inp_sv) {
    for (int idx = threadIdx.x; idx < ROWS * 64; idx += NT) {
        int row = idx >> 6, col = idx & 63;
        float v = 0.f;
        if (col < 39) {
            int comp = (col < 3) ? col : (col - 3) % 3;
            float x = pts[(row0 + row) * 3 + comp];
            if (col < 3) v = x;
            else {
                int b = col - 3; int fi = b / 6; int r = b % 6;
                float a = x * (float)(1 << fi);
                v = (r < 3) ? __sinf(a) : __cosf(a);
            }
        }
        act[fidx(K32OUT, row, col)] = (short)f2bf(v);
        if (inp_sv && col < 39) inp_sv[row * 40 + col] = (short)f2bf(v * INV_SQRT2F);
    }
}

// ---------------- one linear layer: ROWS=128 rows in LDS (fragment-major), 4 waves --
// R11 geometry: 4 waves (1/SIMD), wave w owns t-tiles {w, w+4, ..., w+28} (8 tiles,
// stride-4 so partial-N layers stay balanced) x ALL 8 m-tiles. Unified reg budget
// at 1 wave/SIMD = 512: acc[8][8]=256 AGPR + full dbuf of BOTH streams (bA/bB +
// fA/fB = 128 VGPR) fits with margin -> no spill, and act reads issue one full kc
// ahead, hidden under the 64-MFMA burst (R10 post-mortem: phases ran serial because
// afr loads sat on the critical path and regs were pinned at the 256 cap).
// Act LDS traffic also halves: 4 waves x 128 KB vs 8 x 128 KB per layer.
template<int ACT, int K32IN, int K32OUT, bool FULL>
__device__ void layer_mm(short* act, const ushort* __restrict__ Wf,
                         const float* __restrict__ bias, int Nout, float scale,
                         bool toLds, float* gOut, int gCol0, int gRow0)
{
    const int tid = threadIdx.x;
    const int wave = tid >> 6, lane = tid & 63;
    const int q = lane >> 4, li = lane & 15;
    const int lane8 = lane * 8;
    const int Ttot = FULL ? 32 : ((Nout + 15) >> 4);

    floatx4 acc[8][8];   // [t-tile i][m-tile] = 256 AGPR
#pragma unroll
    for (int i = 0; i < 8; ++i)
#pragma unroll
        for (int m = 0; m < 8; ++m) acc[i][m] = (floatx4){0.f, 0.f, 0.f, 0.f};

    bool tv[8]; const ushort* wb[8];
#pragma unroll
    for (int i = 0; i < 8; ++i) {
        int t = wave + 4 * i;
        tv[i] = FULL ? true : (t < Ttot);
        wb[i] = Wf + (size_t)t * K32IN * 512 + lane8;
    }

    if (FULL || tv[0]) {   // waves with no valid t-tile skip the whole K-loop
        short8 bA[8], bB[8], fA[8], fB[8];
        auto loadB = [&](int kc, short8* bb) {
#pragma unroll
            for (int i = 0; i < 8; ++i)
                if (FULL || tv[i]) bb[i] = *(const short8*)(wb[i] + kc * 512);
        };
        auto loadF = [&](int kc, short8* ff) {
#pragma unroll
            for (int m = 0; m < 8; ++m)
                ff[m] = *(const short8*)&act[(m * K32IN + kc) * 512 + lane8];
        };
        auto mm = [&](short8* bb, short8* ff) {
            __builtin_amdgcn_s_setprio(1);
#pragma unroll
            for (int m = 0; m < 8; ++m)
#pragma unroll
                for (int i = 0; i < 8; ++i)
                    if (FULL || tv[i])
                        acc[i][m] = __builtin_amdgcn_mfma_f32_16x16x32_bf16(
                            bb[i], ff[m], acc[i][m], 0, 0, 0);
            __builtin_amdgcn_s_setprio(0);
        };
        loadB(0, bA); loadF(0, fA);
        for (int kc = 0; kc < K32IN; kc += 2) {
            if (kc + 1 < K32IN) { loadB(kc + 1, bB); loadF(kc + 1, fB); }
            mm(bA, fA);
            if (kc + 2 < K32IN) { loadB(kc + 2, bA); loadF(kc + 2, fA); }
            if (kc + 1 < K32IN) mm(bB, fB);
        }
    }
    bar_lgkm();  // act reads done before epilogue overwrites (LDS-only wait)
#pragma unroll
    for (int i = 0; i < 8; ++i) {
        if (!(FULL || tv[i])) continue;
        const int nb = (wave + 4 * i) * 16 + q * 4;
        if (!FULL && nb >= Nout) continue;
        const bool fullN = FULL || (nb + 4) <= Nout;
        float bs[4];
        if (fullN) {
            float4 b4 = *(const float4*)(bias + nb);
            bs[0] = b4.x; bs[1] = b4.y; bs[2] = b4.z; bs[3] = b4.w;
        } else {
#pragma unroll
            for (int r = 0; r < 4; ++r) bs[r] = (nb + r < Nout) ? bias[nb + r] : 0.f;
        }
        // next-layer fragment coords of this lane's 4 consecutive channels
        const int wbase = ((nb >> 5)) * 512 + ((nb >> 3) & 3) * 128 + li * 8 + (nb & 7);
#pragma unroll
        for (int m = 0; m < 8; ++m) {
            const int row = m * 16 + li;
            float v[4];
#pragma unroll
            for (int r = 0; r < 4; ++r) {
                float x = acc[i][m][r] + bs[r];
                if (ACT == 1) x = softplus100(x);
                else if (ACT == 2) x = fmaxf(x, 0.f);
                else if (ACT == 3) x = tanhf(x);
                v[r] = x * scale;
            }
            if (toLds) {
                if (fullN) {
                    uint2v pk = {pk2bf(v[0], v[1]), pk2bf(v[2], v[3])};
                    *(uint2v*)&act[m * K32OUT * 512 + wbase] = pk;
                } else {
#pragma unroll
                    for (int r = 0; r < 4; ++r)
                        if (nb + r < Nout)
                            act[fidx(K32OUT, row, nb + r)] = (short)f2bf(v[r]);
                }
            } else {
#pragma unroll
                for (int r = 0; r < 4; ++r)
                    if (nb + r < Nout)
                        gOut[(size_t)(gRow0 + row) * 263 + gCol0 + nb + r] = v[r];
            }
        }
    }
}

// ---------------- merged kernel: 256 blocks x 256 thr, 1 block/CU, ONE round ----
// ALL blocks run the same phase order (impl -> multi -> disp): at any instant the
// whole XCD streams the SAME layer's weights -> mostly L2-resident. XCD chunk
// swizzle keeps each XCD's 32 blocks row-contiguous -> ~8 multi-clusters per XCD.
struct IP { int iw[9]; const float* ib[9]; };
struct DMP { int dw[4]; const float* db[4]; int mw[3]; const float* mb[3]; };
struct AllP { IP ip; DMP dm; };

struct LayerCtx {
    short* act; short* inp_sv; const float* pts; float* out; int row0;
};

__device__ void run_impl(LayerCtx& c, const IP& p) {
    embedR<2>(c.act, c.pts, c.row0, c.inp_sv);
    bar_lgkm();
    layer_mm<1, 2, 16, true>(c.act, g_wbuf + p.iw[0], p.ib[0], 512, 1.f, true, nullptr, 0, 0);
    bar_lgkm();
    layer_mm<1, 16, 16, true>(c.act, g_wbuf + p.iw[1], p.ib[1], 512, 1.f, true, nullptr, 0, 0);
    bar_lgkm();
    layer_mm<1, 16, 16, true>(c.act, g_wbuf + p.iw[2], p.ib[2], 512, 1.f, true, nullptr, 0, 0);
    bar_lgkm();
    // layer 3: softplus, then pre-scale by 1/sqrt(2) (skip-concat scale)
    layer_mm<1, 16, 16, false>(c.act, g_wbuf + p.iw[3], p.ib[3], 473, INV_SQRT2F, true, nullptr, 0, 0);
    for (int t2 = threadIdx.x; t2 < ROWS * 64; t2 += NT) {
        int row = t2 >> 6, col = t2 & 63;
        if (col < 39) c.act[fidx(16, row, 473 + col)] = c.inp_sv[row * 40 + col];
    }
    bar_lgkm();
    layer_mm<1, 16, 16, true>(c.act, g_wbuf + p.iw[4], p.ib[4], 512, 1.f, true, nullptr, 0, 0);
    bar_lgkm();
    layer_mm<1, 16, 16, true>(c.act, g_wbuf + p.iw[5], p.ib[5], 512, 1.f, true, nullptr, 0, 0);
    bar_lgkm();
    layer_mm<1, 16, 16, true>(c.act, g_wbuf + p.iw[6], p.ib[6], 512, 1.f, true, nullptr, 0, 0);
    bar_lgkm();
    layer_mm<1, 16, 16, true>(c.act, g_wbuf + p.iw[7], p.ib[7], 512, 1.f, true, nullptr, 0, 0);
    bar_lgkm();
    layer_mm<0, 16, 16, false>(c.act, g_wbuf + p.iw[8], p.ib[8], 257, 1.f, false, c.out, 0, c.row0);
    // epilogue writes global only; act reads finished at internal barrier ->
    // caller may re-embed act without another barrier.
}

__device__ void run_dm(LayerCtx& c, const DMP& p, int rpc) {
    const int cl = c.row0 / rpc;
    const ushort* w0 = g_wbuf + p.mw[0] + cl * 8192;
    const ushort* w1 = g_wbuf + p.mw[1] + cl * 16384;
    const ushort* w2 = g_wbuf + p.mw[2] + cl * 2048;
    // ---- multi displacement (tiny): cluster cl covers this whole 128-row block ----
    embedR<2>(c.act, c.pts, c.row0, nullptr);
    bar_lgkm();
    layer_mm<2, 2, 4, false>(c.act, w0, p.mb[0] + cl * 128, 128, 1.f, true, nullptr, 0, 0);
    bar_lgkm();
    layer_mm<2, 4, 4, false>(c.act, w1, p.mb[1] + cl * 128, 128, 1.f, true, nullptr, 0, 0);
    bar_lgkm();
    layer_mm<3, 4, 4, false>(c.act, w2, p.mb[2] + cl * 3, 3, 1.f, false, c.out, 260, c.row0);
    // ---- displacement network ----
    embedR<2>(c.act, c.pts, c.row0, nullptr);
    bar_lgkm();
    layer_mm<2, 2, 16, true>(c.act, g_wbuf + p.dw[0], p.db[0], 512, 1.f, true, nullptr, 0, 0);
    bar_lgkm();
    layer_mm<2, 16, 16, true>(c.act, g_wbuf + p.dw[1], p.db[1], 512, 1.f, true, nullptr, 0, 0);
    bar_lgkm();
    layer_mm<2, 16, 16, true>(c.act, g_wbuf + p.dw[2], p.db[2], 512, 1.f, true, nullptr, 0, 0);
    bar_lgkm();
    layer_mm<3, 16, 16, false>(c.act, g_wbuf + p.dw[3], p.db[3], 3, 1.f, false, c.out, 257, c.row0);
}

// 4 waves = 1 wave/SIMD -> 512 unified regs/wave (256 AGPR acc + ~170 arch, no
// spill, full operand double-buffering). LDS 138 KB still pins 1 block/CU.
__global__ __launch_bounds__(NT, 1) void k_all(const float* __restrict__ pts,
                                               AllP P, float* __restrict__ out,
                                               int rpc) {
    __shared__ __align__(16) short act[ROWS * 512];   // 128 KB
    __shared__ short inp_sv[ROWS * 40];               // 10 KB
    // T1 bijective XCD chunk swizzle: 256 blocks, 8 XCDs (hw maps bid % 8 -> XCD)
    // -> XCD x owns contiguous row-chunks of 32 blocks. 256 % 8 == 0 -> bijective.
    const int swz = (blockIdx.x & 7) * 32 + (blockIdx.x >> 3);
    LayerCtx c{act, inp_sv, pts, out, swz * ROWS};
    run_impl(c, P.ip);
    run_dm(c, P.dm, rpc);
}

extern "C" void kernel_launch(void* const* d_in, const int* in_sizes, int n_in,
                              void* d_out, int out_size, void* d_ws, size_t ws_size,
                              hipStream_t stream) {
    const float* pts = (const float*)d_in[0];
    float* out = (float*)d_out;
    const int N = in_sizes[0] / 3;       // 32768
    const int rpc = N / 64;              // rows per cluster (512)

    const int iN[9] = {512, 512, 512, 473, 512, 512, 512, 512, 257};
    const int iK[9] = {39, 512, 512, 512, 512, 512, 512, 512, 512};
    const int dN[4] = {512, 512, 512, 3};
    const int dK[4] = {39, 512, 512, 512};
    const int mN[3] = {128, 128, 3};
    const int mK[3] = {39, 128, 128};

    CvtAll cv; AllP P;
    int off = 0, seg = 0;
    auto add_seg = [&](const float* src, int nout, int kw, int nclust) -> int {
        int k32 = ((kw + 31) & ~31) / 32;
        int ttot = (nout + 15) >> 4;
        cv.seg[seg].s = src; cv.seg[seg].off = off;
        cv.seg[seg].nout = nout; cv.seg[seg].kw = kw;
        cv.seg[seg].k32 = k32; cv.seg[seg].ttot = ttot; cv.seg[seg].nclust = nclust;
        int my = off;
        off += ttot * k32 * 512 * nclust;
        ++seg;
        return my;
    };
    for (int l = 0; l < 9; ++l) {
        P.ip.iw[l] = add_seg((const float*)d_in[1 + 2 * l], iN[l], iK[l], 1);
        P.ip.ib[l] = (const float*)d_in[2 + 2 * l];
    }
    for (int l = 0; l < 4; ++l) {
        P.dm.dw[l] = add_seg((const float*)d_in[19 + 2 * l], dN[l], dK[l], 1);
        P.dm.db[l] = (const float*)d_in[20 + 2 * l];
    }
    for (int l = 0; l < 3; ++l) {
        P.dm.mw[l] = add_seg((const float*)d_in[27 + 2 * l], mN[l], mK[l], 64);
        P.dm.mb[l] = (const float*)d_in[28 + 2 * l];
    }

    k_cvt<<<dim3(256, 16), 256, 0, stream>>>(cv);
    k_all<<<N / ROWS, NT, 0, stream>>>(pts, P, out, rpc);
}

// Round 14
// 401.916 us; speedup vs baseline: 2.2675x; 2.2675x over previous
//
#include <hip/hip_runtime.h>
#include <hip/hip_bf16.h>
#include <stdint.h>

typedef __attribute__((ext_vector_type(8))) short short8;
typedef __attribute__((ext_vector_type(4))) float floatx4;
typedef __attribute__((ext_vector_type(2))) uint uint2v;

#define INV_SQRT2F 0.70710678118654752440f
#define ROWS 128
#define NT 512

// fragment-ordered bf16 weights (8.5 MB), filled by k_cvt each call
__device__ ushort g_wbuf[4259840];

__device__ __forceinline__ ushort f2bf(float f) {
    union { float f; uint32_t u; } c; c.f = f;
    uint32_t x = c.u;
    return (ushort)((x + 0x7fffu + ((x >> 16) & 1u)) >> 16);  // RTNE
}
__device__ __forceinline__ uint pk2bf(float a, float b) {   // v_cvt_pk_bf16_f32
    union { __hip_bfloat162 h; uint u; } c;
    c.h = __float22bfloat162_rn(make_float2(a, b));
    return c.u;
}
__device__ __forceinline__ float softplus100(float x) {
    float z = 100.f * x;
    return fmaxf(x, 0.f) + __logf(1.f + __expf(-fabsf(z))) * 0.01f;
}
// barrier that waits only on LDS ops: weight loads (vmcnt) stay in flight
// across it (T4: never drain vmcnt to 0 in the layer loop).
__device__ __forceinline__ void bar_lgkm() {
    asm volatile("s_waitcnt lgkmcnt(0)\n\ts_barrier" ::: "memory");
}
// fragment-major index (in shorts) of (row, ch) for a layout with K32 kc-groups:
// elem j of lane (q*16+li) at (m,kc) is row = m*16+li, ch = kc*32 + q*8 + j.
__device__ __forceinline__ int fidx(int K32, int row, int ch) {
    return (((row >> 4) * K32 + (ch >> 5)) * 64 + ((ch >> 3) & 3) * 16 + (row & 15)) * 8 + (ch & 7);
}

// ---------------- weight cvt + fragment reorder ----------------
struct Seg { const float* s; int off, nout, kw, k32, ttot, nclust; };
struct CvtAll { Seg seg[16]; };

__global__ void k_cvt(CvtAll c) {
    Seg sg = c.seg[blockIdx.y];
    ushort* d = g_wbuf + sg.off;
    const int pcs8 = sg.ttot * sg.k32 * 64;
    const int tot8 = pcs8 * sg.nclust;
    const bool vec = ((sg.kw & 7) == 0);   // full-width aligned path (kw=512/128)
    for (int i8 = blockIdx.x * blockDim.x + threadIdx.x; i8 < tot8;
         i8 += gridDim.x * blockDim.x) {
        int cl = i8 / pcs8;
        int r = i8 - cl * pcs8;
        int t = r / (sg.k32 * 64);
        int r2 = r - t * (sg.k32 * 64);
        int kc = r2 >> 6;
        int lane = r2 & 63;
        int n = t * 16 + (lane & 15);
        int kb = kc * 32 + (lane >> 4) * 8;
        const float* src = sg.s + (size_t)cl * sg.nout * sg.kw;
        short8 v = {0, 0, 0, 0, 0, 0, 0, 0};
        if (n < sg.nout) {
            if (vec && kb + 8 <= sg.kw) {
                // 2x dwordx4 instead of 8 scalar loads (16B-aligned: kw%8==0, kb%8==0)
                const float4* s4 = (const float4*)(src + (size_t)n * sg.kw + kb);
                float4 a = s4[0], b = s4[1];
                v[0] = (short)f2bf(a.x); v[1] = (short)f2bf(a.y);
                v[2] = (short)f2bf(a.z); v[3] = (short)f2bf(a.w);
                v[4] = (short)f2bf(b.x); v[5] = (short)f2bf(b.y);
                v[6] = (short)f2bf(b.z); v[7] = (short)f2bf(b.w);
            } else {
#pragma unroll
                for (int j = 0; j < 8; ++j) {
                    int k = kb + j;
                    if (k < sg.kw) v[j] = (short)f2bf(src[(size_t)n * sg.kw + k]);
                }
            }
        }
        *(short8*)(d + (size_t)i8 * 8) = v;
    }
}

// ---------------- embedding: ROWS rows, cols 0..63 (zeros beyond 38) ----------------
template<int K32OUT>
__device__ void embedR(short* act, const float* pts, int row0, short* inp_sv) {
    for (int idx = threadIdx.x; idx < ROWS * 64; idx += NT) {
        int row = idx >> 6, col = idx & 63;
        float v = 0.f;
        if (col < 39) {
            int comp = (col < 3) ? col : (col - 3) % 3;
            float x = pts[(row0 + row) * 3 + comp];
            if (col < 3) v = x;
            else {
                int b = col - 3; int fi = b / 6; int r = b % 6;
                float a = x * (float)(1 << fi);
                v = (r < 3) ? __sinf(a) : __cosf(a);
            }
        }
        act[fidx(K32OUT, row, col)] = (short)f2bf(v);
        if (inp_sv && col < 39) inp_sv[row * 40 + col] = (short)f2bf(v * INV_SQRT2F);
    }
}

// ---------------- one linear layer: ROWS=128 rows in LDS (fragment-major), 8 waves --
// R13 geometry: 8 waves = 4 t-groups (wg) x 2 m-groups (mg). Wave owns t-tiles
// {wg, wg+4, ..., wg+28} (8, stride-4 for partial-N balance) x m-tiles
// {mg*4..mg*4+3}. acc[8][4] = 128 AGPR (R10's proven-safe budget) while act LDS
// reads HALVE vs R10 (4 afr/kc/wave, shared across both t-halves): 512 b128/CU/
// layer vs 1024 — R10's pipe accounting showed LDS+VALU+MFMA busy-times summing
// to wall time (serial), with LDS the largest term. Weight tiles are read by the
// 2 mg-waves (same lines, same window -> L1 absorbs the duplicate).
// Half-t ping-pong keeps live VGPRs ~75 (bA+bB+afr=48): spill impossible (R12
// lesson: the 256-AGPR/full-dbuf point spills catastrophically).
template<int ACT, int K32IN, int K32OUT, bool FULL>
__device__ void layer_mm(short* act, const ushort* __restrict__ Wf,
                         const float* __restrict__ bias, int Nout, float scale,
                         bool toLds, float* gOut, int gCol0, int gRow0)
{
    const int tid = threadIdx.x;
    const int wave = tid >> 6, lane = tid & 63;
    const int wg = wave & 3, mg = wave >> 2;
    const int q = lane >> 4, li = lane & 15;
    const int lane8 = lane * 8;
    const int Ttot = FULL ? 32 : ((Nout + 15) >> 4);

    floatx4 acc[8][4];   // [t-tile i][m-tile m2] = 128 AGPR
#pragma unroll
    for (int i = 0; i < 8; ++i)
#pragma unroll
        for (int m = 0; m < 4; ++m) acc[i][m] = (floatx4){0.f, 0.f, 0.f, 0.f};

    bool tv[8]; const ushort* wb[8];
#pragma unroll
    for (int i = 0; i < 8; ++i) {
        int t = wg + 4 * i;
        tv[i] = FULL ? true : (t < Ttot);
        wb[i] = Wf + (size_t)t * K32IN * 512 + lane8;
    }

    if (FULL || tv[0]) {   // waves with no valid t-tile skip the whole K-loop
        short8 bA[4], bB[4], afr[4];
        auto loadB4 = [&](int kc, int half, short8* bb) {
#pragma unroll
            for (int j = 0; j < 4; ++j) {
                int i = half * 4 + j;
                if (FULL || tv[i]) bb[j] = *(const short8*)(wb[i] + kc * 512);
            }
        };
        auto loadF = [&](int kc) {
#pragma unroll
            for (int m2 = 0; m2 < 4; ++m2)
                afr[m2] = *(const short8*)
                    &act[((mg * 4 + m2) * K32IN + kc) * 512 + lane8];
        };
        auto mmH = [&](short8* bb, int half) {
            __builtin_amdgcn_s_setprio(1);   // T5: favor MFMA waves
#pragma unroll
            for (int j = 0; j < 4; ++j) {
                int i = half * 4 + j;
                if (!(FULL || tv[i])) continue;
#pragma unroll
                for (int m2 = 0; m2 < 4; ++m2)
                    acc[i][m2] = __builtin_amdgcn_mfma_f32_16x16x32_bf16(
                        bb[j], afr[m2], acc[i][m2], 0, 0, 0);
            }
            __builtin_amdgcn_s_setprio(0);
        };

        loadB4(0, 0, bA);
        loadB4(0, 1, bB);
        for (int kc = 0; kc < K32IN; ++kc) {
            loadF(kc);                               // 4 ds_reads, shared by halves
            mmH(bA, 0);                              // 16 MFMA
            if (kc + 1 < K32IN) loadB4(kc + 1, 0, bA);  // ~120 cyc cover below
            mmH(bB, 1);                              // 16 MFMA
            if (kc + 1 < K32IN) loadB4(kc + 1, 1, bB);  // covered by next loadF+mmH
        }
    }
    bar_lgkm();  // act reads done before epilogue overwrites (LDS-only wait)
#pragma unroll
    for (int i = 0; i < 8; ++i) {
        if (!(FULL || tv[i])) continue;
        const int nb = (wg + 4 * i) * 16 + q * 4;
        if (!FULL && nb >= Nout) continue;
        const bool fullN = FULL || (nb + 4) <= Nout;
        float bs[4];
        if (fullN) {
            float4 b4 = *(const float4*)(bias + nb);
            bs[0] = b4.x; bs[1] = b4.y; bs[2] = b4.z; bs[3] = b4.w;
        } else {
#pragma unroll
            for (int r = 0; r < 4; ++r) bs[r] = (nb + r < Nout) ? bias[nb + r] : 0.f;
        }
        // next-layer fragment coords of this lane's 4 consecutive channels
        const int wbase = ((nb >> 5)) * 512 + ((nb >> 3) & 3) * 128 + li * 8 + (nb & 7);
#pragma unroll
        for (int m2 = 0; m2 < 4; ++m2) {
            const int mAbs = mg * 4 + m2;
            const int row = mAbs * 16 + li;
            float v[4];
#pragma unroll
            for (int r = 0; r < 4; ++r) {
                float x = acc[i][m2][r] + bs[r];
                if (ACT == 1) x = softplus100(x);
                else if (ACT == 2) x = fmaxf(x, 0.f);
                else if (ACT == 3) x = tanhf(x);
                v[r] = x * scale;
            }
            if (toLds) {
                if (fullN) {
                    uint2v pk = {pk2bf(v[0], v[1]), pk2bf(v[2], v[3])};
                    *(uint2v*)&act[mAbs * K32OUT * 512 + wbase] = pk;
                } else {
#pragma unroll
                    for (int r = 0; r < 4; ++r)
                        if (nb + r < Nout)
                            act[fidx(K32OUT, row, nb + r)] = (short)f2bf(v[r]);
                }
            } else {
#pragma unroll
                for (int r = 0; r < 4; ++r)
                    if (nb + r < Nout)
                        gOut[(size_t)(gRow0 + row) * 263 + gCol0 + nb + r] = v[r];
            }
        }
    }
}

// ---------------- merged kernel: 256 blocks x 512 thr, 1 block/CU, ONE round ----
// ALL blocks run the same phase order (impl -> multi -> disp): at any instant the
// whole XCD streams the SAME layer's weights -> mostly L2-resident. XCD chunk
// swizzle keeps each XCD's 32 blocks row-contiguous -> ~8 multi-clusters per XCD.
struct IP { int iw[9]; const float* ib[9]; };
struct DMP { int dw[4]; const float* db[4]; int mw[3]; const float* mb[3]; };
struct AllP { IP ip; DMP dm; };

struct LayerCtx {
    short* act; short* inp_sv; const float* pts; float* out; int row0;
};

__device__ void run_impl(LayerCtx& c, const IP& p) {
    embedR<2>(c.act, c.pts, c.row0, c.inp_sv);
    bar_lgkm();
    layer_mm<1, 2, 16, true>(c.act, g_wbuf + p.iw[0], p.ib[0], 512, 1.f, true, nullptr, 0, 0);
    bar_lgkm();
    layer_mm<1, 16, 16, true>(c.act, g_wbuf + p.iw[1], p.ib[1], 512, 1.f, true, nullptr, 0, 0);
    bar_lgkm();
    layer_mm<1, 16, 16, true>(c.act, g_wbuf + p.iw[2], p.ib[2], 512, 1.f, true, nullptr, 0, 0);
    bar_lgkm();
    // layer 3: softplus, then pre-scale by 1/sqrt(2) (skip-concat scale)
    layer_mm<1, 16, 16, false>(c.act, g_wbuf + p.iw[3], p.ib[3], 473, INV_SQRT2F, true, nullptr, 0, 0);
    for (int t2 = threadIdx.x; t2 < ROWS * 64; t2 += NT) {
        int row = t2 >> 6, col = t2 & 63;
        if (col < 39) c.act[fidx(16, row, 473 + col)] = c.inp_sv[row * 40 + col];
    }
    bar_lgkm();
    layer_mm<1, 16, 16, true>(c.act, g_wbuf + p.iw[4], p.ib[4], 512, 1.f, true, nullptr, 0, 0);
    bar_lgkm();
    layer_mm<1, 16, 16, true>(c.act, g_wbuf + p.iw[5], p.ib[5], 512, 1.f, true, nullptr, 0, 0);
    bar_lgkm();
    layer_mm<1, 16, 16, true>(c.act, g_wbuf + p.iw[6], p.ib[6], 512, 1.f, true, nullptr, 0, 0);
    bar_lgkm();
    layer_mm<1, 16, 16, true>(c.act, g_wbuf + p.iw[7], p.ib[7], 512, 1.f, true, nullptr, 0, 0);
    bar_lgkm();
    layer_mm<0, 16, 16, false>(c.act, g_wbuf + p.iw[8], p.ib[8], 257, 1.f, false, c.out, 0, c.row0);
    // epilogue writes global only; act reads finished at internal barrier ->
    // caller may re-embed act without another barrier.
}

__device__ void run_dm(LayerCtx& c, const DMP& p, int rpc) {
    const int cl = c.row0 / rpc;
    const ushort* w0 = g_wbuf + p.mw[0] + cl * 8192;
    const ushort* w1 = g_wbuf + p.mw[1] + cl * 16384;
    const ushort* w2 = g_wbuf + p.mw[2] + cl * 2048;
    // ---- multi displacement (tiny): cluster cl covers this whole 128-row block ----
    embedR<2>(c.act, c.pts, c.row0, nullptr);
    bar_lgkm();
    layer_mm<2, 2, 4, false>(c.act, w0, p.mb[0] + cl * 128, 128, 1.f, true, nullptr, 0, 0);
    bar_lgkm();
    layer_mm<2, 4, 4, false>(c.act, w1, p.mb[1] + cl * 128, 128, 1.f, true, nullptr, 0, 0);
    bar_lgkm();
    layer_mm<3, 4, 4, false>(c.act, w2, p.mb[2] + cl * 3, 3, 1.f, false, c.out, 260, c.row0);
    // ---- displacement network ----
    embedR<2>(c.act, c.pts, c.row0, nullptr);
    bar_lgkm();
    layer_mm<2, 2, 16, true>(c.act, g_wbuf + p.dw[0], p.db[0], 512, 1.f, true, nullptr, 0, 0);
    bar_lgkm();
    layer_mm<2, 16, 16, true>(c.act, g_wbuf + p.dw[1], p.db[1], 512, 1.f, true, nullptr, 0, 0);
    bar_lgkm();
    layer_mm<2, 16, 16, true>(c.act, g_wbuf + p.dw[2], p.db[2], 512, 1.f, true, nullptr, 0, 0);
    bar_lgkm();
    layer_mm<3, 16, 16, false>(c.act, g_wbuf + p.dw[3], p.db[3], 3, 1.f, false, c.out, 257, c.row0);
}

// 8 waves = 2 waves/SIMD -> 256 unified regs/wave (128 AGPR acc + ~75 arch live:
// headroom, no spill). LDS 138 KB still pins 1 block/CU.
__global__ __launch_bounds__(NT, 2) void k_all(const float* __restrict__ pts,
                                               AllP P, float* __restrict__ out,
                                               int rpc) {
    __shared__ __align__(16) short act[ROWS * 512];   // 128 KB
    __shared__ short inp_sv[ROWS * 40];               // 10 KB
    // T1 bijective XCD chunk swizzle: 256 blocks, 8 XCDs (hw maps bid % 8 -> XCD)
    // -> XCD x owns contiguous row-chunks of 32 blocks. 256 % 8 == 0 -> bijective.
    const int swz = (blockIdx.x & 7) * 32 + (blockIdx.x >> 3);
    LayerCtx c{act, inp_sv, pts, out, swz * ROWS};
    run_impl(c, P.ip);
    run_dm(c, P.dm, rpc);
}

extern "C" void kernel_launch(void* const* d_in, const int* in_sizes, int n_in,
                              void* d_out, int out_size, void* d_ws, size_t ws_size,
                              hipStream_t stream) {
    const float* pts = (const float*)d_in[0];
    float* out = (float*)d_out;
    const int N = in_sizes[0] / 3;       // 32768
    const int rpc = N / 64;              // rows per cluster (512)

    const int iN[9] = {512, 512, 512, 473, 512, 512, 512, 512, 257};
    const int iK[9] = {39, 512, 512, 512, 512, 512, 512, 512, 512};
    const int dN[4] = {512, 512, 512, 3};
    const int dK[4] = {39, 512, 512, 512};
    const int mN[3] = {128, 128, 3};
    const int mK[3] = {39, 128, 128};

    CvtAll cv; AllP P;
    int off = 0, seg = 0;
    auto add_seg = [&](const float* src, int nout, int kw, int nclust) -> int {
        int k32 = ((kw + 31) & ~31) / 32;
        int ttot = (nout + 15) >> 4;
        cv.seg[seg].s = src; cv.seg[seg].off = off;
        cv.seg[seg].nout = nout; cv.seg[seg].kw = kw;
        cv.seg[seg].k32 = k32; cv.seg[seg].ttot = ttot; cv.seg[seg].nclust = nclust;
        int my = off;
        off += ttot * k32 * 512 * nclust;
        ++seg;
        return my;
    };
    for (int l = 0; l < 9; ++l) {
        P.ip.iw[l] = add_seg((const float*)d_in[1 + 2 * l], iN[l], iK[l], 1);
        P.ip.ib[l] = (const float*)d_in[2 + 2 * l];
    }
    for (int l = 0; l < 4; ++l) {
        P.dm.dw[l] = add_seg((const float*)d_in[19 + 2 * l], dN[l], dK[l], 1);
        P.dm.db[l] = (const float*)d_in[20 + 2 * l];
    }
    for (int l = 0; l < 3; ++l) {
        P.dm.mw[l] = add_seg((const float*)d_in[27 + 2 * l], mN[l], mK[l], 64);
        P.dm.mb[l] = (const float*)d_in[28 + 2 * l];
    }

    k_cvt<<<dim3(256, 16), 256, 0, stream>>>(cv);
    k_all<<<N / ROWS, NT, 0, stream>>>(pts, P, out, rpc);
}

// Round 19
// 386.905 us; speedup vs baseline: 2.3554x; 1.0388x over previous
//
#include <hip/hip_runtime.h>
#include <hip/hip_bf16.h>
#include <stdint.h>

typedef __attribute__((ext_vector_type(8))) short short8;
typedef __attribute__((ext_vector_type(4))) float floatx4;
typedef __attribute__((ext_vector_type(2))) uint uint2v;

#define INV_SQRT2F 0.70710678118654752440f
#define ROWS 64
#define NT 256

// fragment-ordered bf16 weights (8.5 MB), filled by k_cvt each call
__device__ ushort g_wbuf[4259840];

__device__ __forceinline__ ushort f2bf(float f) {
    union { float f; uint32_t u; } c; c.f = f;
    uint32_t x = c.u;
    return (ushort)((x + 0x7fffu + ((x >> 16) & 1u)) >> 16);  // RTNE
}
__device__ __forceinline__ uint pk2bf(float a, float b) {   // v_cvt_pk_bf16_f32
    union { __hip_bfloat162 h; uint u; } c;
    c.h = __float22bfloat162_rn(make_float2(a, b));
    return c.u;
}
__device__ __forceinline__ float softplus100(float x) {
    float z = 100.f * x;
    return fmaxf(x, 0.f) + __logf(1.f + __expf(-fabsf(z))) * 0.01f;
}
// barrier that waits only on LDS ops: weight loads (vmcnt) stay in flight
// across it (T4: never drain vmcnt to 0 in the layer loop).
__device__ __forceinline__ void bar_lgkm() {
    asm volatile("s_waitcnt lgkmcnt(0)\n\ts_barrier" ::: "memory");
}
// fragment-major index (in shorts) of (row, ch) for a layout with K32 kc-groups:
// elem j of lane (q*16+li) at (m,kc) is row = m*16+li, ch = kc*32 + q*8 + j.
__device__ __forceinline__ int fidx(int K32, int row, int ch) {
    return (((row >> 4) * K32 + (ch >> 5)) * 64 + ((ch >> 3) & 3) * 16 + (row & 15)) * 8 + (ch & 7);
}

// ---------------- weight cvt + fragment reorder ----------------
struct Seg { const float* s; int off, nout, kw, k32, ttot, nclust; };
struct CvtAll { Seg seg[16]; };

__global__ void k_cvt(CvtAll c) {
    Seg sg = c.seg[blockIdx.y];
    ushort* d = g_wbuf + sg.off;
    const int pcs8 = sg.ttot * sg.k32 * 64;
    const int tot8 = pcs8 * sg.nclust;
    const bool vec = ((sg.kw & 7) == 0);   // full-width aligned path (kw=512/128)
    for (int i8 = blockIdx.x * blockDim.x + threadIdx.x; i8 < tot8;
         i8 += gridDim.x * blockDim.x) {
        int cl = i8 / pcs8;
        int r = i8 - cl * pcs8;
        int t = r / (sg.k32 * 64);
        int r2 = r - t * (sg.k32 * 64);
        int kc = r2 >> 6;
        int lane = r2 & 63;
        int n = t * 16 + (lane & 15);
        int kb = kc * 32 + (lane >> 4) * 8;
        const float* src = sg.s + (size_t)cl * sg.nout * sg.kw;
        short8 v = {0, 0, 0, 0, 0, 0, 0, 0};
        if (n < sg.nout) {
            if (vec && kb + 8 <= sg.kw) {
                // 2x dwordx4 instead of 8 scalar loads (16B-aligned: kw%8==0, kb%8==0)
                const float4* s4 = (const float4*)(src + (size_t)n * sg.kw + kb);
                float4 a = s4[0], b = s4[1];
                v[0] = (short)f2bf(a.x); v[1] = (short)f2bf(a.y);
                v[2] = (short)f2bf(a.z); v[3] = (short)f2bf(a.w);
                v[4] = (short)f2bf(b.x); v[5] = (short)f2bf(b.y);
                v[6] = (short)f2bf(b.z); v[7] = (short)f2bf(b.w);
            } else {
#pragma unroll
                for (int j = 0; j < 8; ++j) {
                    int k = kb + j;
                    if (k < sg.kw) v[j] = (short)f2bf(src[(size_t)n * sg.kw + k]);
                }
            }
        }
        *(short8*)(d + (size_t)i8 * 8) = v;
    }
}

// ---------------- embedding: ROWS rows, cols 0..63 (zeros beyond 38) ----------------
template<int K32OUT>
__device__ void embedR(short* act, const float* pts, int row0, short* inp_sv) {
    for (int idx = threadIdx.x; idx < ROWS * 64; idx += NT) {
        int row = idx >> 6, col = idx & 63;
        float v = 0.f;
        if (col < 39) {
            int comp = (col < 3) ? col : (col - 3) % 3;
            float x = pts[(row0 + row) * 3 + comp];
            if (col < 3) v = x;
            else {
                int b = col - 3; int fi = b / 6; int r = b % 6;
                float a = x * (float)(1 << fi);
                v = (r < 3) ? __sinf(a) : __cosf(a);
            }
        }
        act[fidx(K32OUT, row, col)] = (short)f2bf(v);
        if (inp_sv && col < 39) inp_sv[row * 40 + col] = (short)f2bf(v * INV_SQRT2F);
    }
}

// ---------------- one linear layer: ROWS=64 rows in LDS (fragment-major), 4 waves --
// R15 geometry: 64-row block, 4 waves. Wave w owns t-tiles {w, w+4, ..., w+28}
// (8, stride-4 for partial-N balance) x ALL 4 m-tiles. acc[8][4] = 128 AGPR —
// R14's proven-safe register point, identical per-CU traffic (2 blocks/CU:
// act reads 512 b128/CU/layer, weight tiles read by 2 co-resident blocks that
// share L1/L2 lines). The win vs R14: the two 64-row halves are now SEPARATE
// BLOCKS with independent barriers -> block A's epilogue VALU (softplus) overlaps
// block B's K-loop MFMA instead of serializing behind a common barrier (R14
// counters: VALU 44% + MFMA 25% busy but ~30% wait -> near-serial phases).
template<int ACT, int K32IN, int K32OUT, bool FULL>
__device__ void layer_mm(short* act, const ushort* __restrict__ Wf,
                         const float* __restrict__ bias, int Nout, float scale,
                         bool toLds, float* gOut, int gCol0, int gRow0)
{
    const int tid = threadIdx.x;
    const int wave = tid >> 6, lane = tid & 63;
    const int q = lane >> 4, li = lane & 15;
    const int lane8 = lane * 8;
    const int Ttot = FULL ? 32 : ((Nout + 15) >> 4);

    floatx4 acc[8][4];   // [t-tile i][m-tile m2] = 128 AGPR
#pragma unroll
    for (int i = 0; i < 8; ++i)
#pragma unroll
        for (int m = 0; m < 4; ++m) acc[i][m] = (floatx4){0.f, 0.f, 0.f, 0.f};

    bool tv[8]; const ushort* wb[8];
#pragma unroll
    for (int i = 0; i < 8; ++i) {
        int t = wave + 4 * i;
        tv[i] = FULL ? true : (t < Ttot);
        wb[i] = Wf + (size_t)t * K32IN * 512 + lane8;
    }

    if (FULL || tv[0]) {   // waves with no valid t-tile skip the whole K-loop
        short8 bA[4], bB[4], afr[4];
        auto loadB4 = [&](int kc, int half, short8* bb) {
#pragma unroll
            for (int j = 0; j < 4; ++j) {
                int i = half * 4 + j;
                if (FULL || tv[i]) bb[j] = *(const short8*)(wb[i] + kc * 512);
            }
        };
        auto loadF = [&](int kc) {
#pragma unroll
            for (int m2 = 0; m2 < 4; ++m2)
                afr[m2] = *(const short8*)&act[(m2 * K32IN + kc) * 512 + lane8];
        };
        auto mmH = [&](short8* bb, int half) {
            __builtin_amdgcn_s_setprio(1);   // T5: favor MFMA waves
#pragma unroll
            for (int j = 0; j < 4; ++j) {
                int i = half * 4 + j;
                if (!(FULL || tv[i])) continue;
#pragma unroll
                for (int m2 = 0; m2 < 4; ++m2)
                    acc[i][m2] = __builtin_amdgcn_mfma_f32_16x16x32_bf16(
                        bb[j], afr[m2], acc[i][m2], 0, 0, 0);
            }
            __builtin_amdgcn_s_setprio(0);
        };

        loadB4(0, 0, bA);
        loadB4(0, 1, bB);
        for (int kc = 0; kc < K32IN; ++kc) {
            loadF(kc);                               // 4 ds_reads, shared by halves
            mmH(bA, 0);                              // 16 MFMA
            if (kc + 1 < K32IN) loadB4(kc + 1, 0, bA);  // ~120 cyc cover below
            mmH(bB, 1);                              // 16 MFMA
            if (kc + 1 < K32IN) loadB4(kc + 1, 1, bB);  // covered by next loadF+mmH
        }
    }
    bar_lgkm();  // act reads done before epilogue overwrites (LDS-only wait)
#pragma unroll
    for (int i = 0; i < 8; ++i) {
        if (!(FULL || tv[i])) continue;
        const int nb = (wave + 4 * i) * 16 + q * 4;
        if (!FULL && nb >= Nout) continue;
        const bool fullN = FULL || (nb + 4) <= Nout;
        float bs[4];
        if (fullN) {
            float4 b4 = *(const float4*)(bias + nb);
            bs[0] = b4.x; bs[1] = b4.y; bs[2] = b4.z; bs[3] = b4.w;
        } else {
#pragma unroll
            for (int r = 0; r < 4; ++r) bs[r] = (nb + r < Nout) ? bias[nb + r] : 0.f;
        }
        // next-layer fragment coords of this lane's 4 consecutive channels
        const int wbase = ((nb >> 5)) * 512 + ((nb >> 3) & 3) * 128 + li * 8 + (nb & 7);
#pragma unroll
        for (int m2 = 0; m2 < 4; ++m2) {
            const int row = m2 * 16 + li;
            float v[4];
#pragma unroll
            for (int r = 0; r < 4; ++r) {
                float x = acc[i][m2][r] + bs[r];
                if (ACT == 1) x = softplus100(x);
                else if (ACT == 2) x = fmaxf(x, 0.f);
                else if (ACT == 3) x = tanhf(x);
                v[r] = x * scale;
            }
            if (toLds) {
                if (fullN) {
                    uint2v pk = {pk2bf(v[0], v[1]), pk2bf(v[2], v[3])};
                    *(uint2v*)&act[m2 * K32OUT * 512 + wbase] = pk;
                } else {
#pragma unroll
                    for (int r = 0; r < 4; ++r)
                        if (nb + r < Nout)
                            act[fidx(K32OUT, row, nb + r)] = (short)f2bf(v[r]);
                }
            } else {
#pragma unroll
                for (int r = 0; r < 4; ++r)
                    if (nb + r < Nout)
                        gOut[(size_t)(gRow0 + row) * 263 + gCol0 + nb + r] = v[r];
            }
        }
    }
}

// ---------------- merged kernel: 512 blocks x 256 thr, 2 blocks/CU, ONE round ----
// ALL blocks run the same phase order (impl -> multi -> disp): at any instant the
// whole XCD streams the SAME layer's weights -> mostly L2-resident; co-resident
// block pairs share the same weight lines. Independent barriers let the pair's
// epilogue/K-loop phases overlap. XCD chunk swizzle keeps each XCD's 64 blocks
// row-contiguous -> ~8 multi-clusters per XCD.
struct IP { int iw[9]; const float* ib[9]; };
struct DMP { int dw[4]; const float* db[4]; int mw[3]; const float* mb[3]; };
struct AllP { IP ip; DMP dm; };

struct LayerCtx {
    short* act; short* inp_sv; const float* pts; float* out; int row0;
};

__device__ void run_impl(LayerCtx& c, const IP& p) {
    embedR<2>(c.act, c.pts, c.row0, c.inp_sv);
    bar_lgkm();
    layer_mm<1, 2, 16, true>(c.act, g_wbuf + p.iw[0], p.ib[0], 512, 1.f, true, nullptr, 0, 0);
    bar_lgkm();
    layer_mm<1, 16, 16, true>(c.act, g_wbuf + p.iw[1], p.ib[1], 512, 1.f, true, nullptr, 0, 0);
    bar_lgkm();
    layer_mm<1, 16, 16, true>(c.act, g_wbuf + p.iw[2], p.ib[2], 512, 1.f, true, nullptr, 0, 0);
    bar_lgkm();
    // layer 3: softplus, then pre-scale by 1/sqrt(2) (skip-concat scale)
    layer_mm<1, 16, 16, false>(c.act, g_wbuf + p.iw[3], p.ib[3], 473, INV_SQRT2F, true, nullptr, 0, 0);
    for (int t2 = threadIdx.x; t2 < ROWS * 64; t2 += NT) {
        int row = t2 >> 6, col = t2 & 63;
        if (col < 39) c.act[fidx(16, row, 473 + col)] = c.inp_sv[row * 40 + col];
    }
    bar_lgkm();
    layer_mm<1, 16, 16, true>(c.act, g_wbuf + p.iw[4], p.ib[4], 512, 1.f, true, nullptr, 0, 0);
    bar_lgkm();
    layer_mm<1, 16, 16, true>(c.act, g_wbuf + p.iw[5], p.ib[5], 512, 1.f, true, nullptr, 0, 0);
    bar_lgkm();
    layer_mm<1, 16, 16, true>(c.act, g_wbuf + p.iw[6], p.ib[6], 512, 1.f, true, nullptr, 0, 0);
    bar_lgkm();
    layer_mm<1, 16, 16, true>(c.act, g_wbuf + p.iw[7], p.ib[7], 512, 1.f, true, nullptr, 0, 0);
    bar_lgkm();
    layer_mm<0, 16, 16, false>(c.act, g_wbuf + p.iw[8], p.ib[8], 257, 1.f, false, c.out, 0, c.row0);
    // epilogue writes global only; act reads finished at internal barrier ->
    // caller may re-embed act without another barrier.
}

__device__ void run_dm(LayerCtx& c, const DMP& p, int rpc) {
    const int cl = c.row0 / rpc;
    const ushort* w0 = g_wbuf + p.mw[0] + cl * 8192;
    const ushort* w1 = g_wbuf + p.mw[1] + cl * 16384;
    const ushort* w2 = g_wbuf + p.mw[2] + cl * 2048;
    // ---- multi displacement (tiny): cluster cl covers this whole 64-row block ----
    embedR<2>(c.act, c.pts, c.row0, nullptr);
    bar_lgkm();
    layer_mm<2, 2, 4, false>(c.act, w0, p.mb[0] + cl * 128, 128, 1.f, true, nullptr, 0, 0);
    bar_lgkm();
    layer_mm<2, 4, 4, false>(c.act, w1, p.mb[1] + cl * 128, 128, 1.f, true, nullptr, 0, 0);
    bar_lgkm();
    layer_mm<3, 4, 4, false>(c.act, w2, p.mb[2] + cl * 3, 3, 1.f, false, c.out, 260, c.row0);
    // ---- displacement network ----
    embedR<2>(c.act, c.pts, c.row0, nullptr);
    bar_lgkm();
    layer_mm<2, 2, 16, true>(c.act, g_wbuf + p.dw[0], p.db[0], 512, 1.f, true, nullptr, 0, 0);
    bar_lgkm();
    layer_mm<2, 16, 16, true>(c.act, g_wbuf + p.dw[1], p.db[1], 512, 1.f, true, nullptr, 0, 0);
    bar_lgkm();
    layer_mm<2, 16, 16, true>(c.act, g_wbuf + p.dw[2], p.db[2], 512, 1.f, true, nullptr, 0, 0);
    bar_lgkm();
    layer_mm<3, 16, 16, false>(c.act, g_wbuf + p.dw[3], p.db[3], 3, 1.f, false, c.out, 257, c.row0);
}

// 256 threads = 4 waves; 2 blocks/CU = 2 waves/SIMD -> 256 unified regs/wave
// (128 AGPR acc + 128 arch: R14's proven-safe point). LDS 69KB x 2 = 138KB/CU.
__global__ __launch_bounds__(NT, 2) void k_all(const float* __restrict__ pts,
                                               AllP P, float* __restrict__ out,
                                               int rpc) {
    __shared__ __align__(16) short act[ROWS * 512];   // 64 KB
    __shared__ short inp_sv[ROWS * 40];               // 5 KB
    // T1 bijective XCD chunk swizzle: 512 blocks, 8 XCDs (hw maps bid % 8 -> XCD)
    // -> XCD x owns contiguous row-chunks of 64 blocks. 512 % 8 == 0 -> bijective.
    const int swz = (blockIdx.x & 7) * 64 + (blockIdx.x >> 3);
    LayerCtx c{act, inp_sv, pts, out, swz * ROWS};
    run_impl(c, P.ip);
    run_dm(c, P.dm, rpc);
}

extern "C" void kernel_launch(void* const* d_in, const int* in_sizes, int n_in,
                              void* d_out, int out_size, void* d_ws, size_t ws_size,
                              hipStream_t stream) {
    const float* pts = (const float*)d_in[0];
    float* out = (float*)d_out;
    const int N = in_sizes[0] / 3;       // 32768
    const int rpc = N / 64;              // rows per cluster (512)

    const int iN[9] = {512, 512, 512, 473, 512, 512, 512, 512, 257};
    const int iK[9] = {39, 512, 512, 512, 512, 512, 512, 512, 512};
    const int dN[4] = {512, 512, 512, 3};
    const int dK[4] = {39, 512, 512, 512};
    const int mN[3] = {128, 128, 3};
    const int mK[3] = {39, 128, 128};

    CvtAll cv; AllP P;
    int off = 0, seg = 0;
    auto add_seg = [&](const float* src, int nout, int kw, int nclust) -> int {
        int k32 = ((kw + 31) & ~31) / 32;
        int ttot = (nout + 15) >> 4;
        cv.seg[seg].s = src; cv.seg[seg].off = off;
        cv.seg[seg].nout = nout; cv.seg[seg].kw = kw;
        cv.seg[seg].k32 = k32; cv.seg[seg].ttot = ttot; cv.seg[seg].nclust = nclust;
        int my = off;
        off += ttot * k32 * 512 * nclust;
        ++seg;
        return my;
    };
    for (int l = 0; l < 9; ++l) {
        P.ip.iw[l] = add_seg((const float*)d_in[1 + 2 * l], iN[l], iK[l], 1);
        P.ip.ib[l] = (const float*)d_in[2 + 2 * l];
    }
    for (int l = 0; l < 4; ++l) {
        P.dm.dw[l] = add_seg((const float*)d_in[19 + 2 * l], dN[l], dK[l], 1);
        P.dm.db[l] = (const float*)d_in[20 + 2 * l];
    }
    for (int l = 0; l < 3; ++l) {
        P.dm.mw[l] = add_seg((const float*)d_in[27 + 2 * l], mN[l], mK[l], 64);
        P.dm.mb[l] = (const float*)d_in[28 + 2 * l];
    }

    k_cvt<<<dim3(256, 16), 256, 0, stream>>>(cv);
    k_all<<<N / ROWS, NT, 0, stream>>>(pts, P, out, rpc);
}